// Round 7
// baseline (373.286 us; speedup 1.0000x reference)
//
#include <hip/hip_runtime.h>
#include <hip/hip_bf16.h>
#include <math.h>

typedef __attribute__((ext_vector_type(8))) short short8;
typedef __attribute__((ext_vector_type(4))) float f32x4;

// ---------------- workspace layout (bytes) ----------------
#define W1P_OFF   0u          // 128*12*64*8 bf16 = 1,572,864 B
#define W2P_OFF   1572864u    // 128*8*64*8  bf16 = 1,048,576 B
#define W3P_OFF   2621440u
#define W4P_OFF   3670016u    // 128*8*256*8 bf16 = 4,194,304 B
#define EI_OFF    7864320u    // 128*2*32 f32 = 32,768 B
#define RECIP_OFF 7897088u    // 2048 f32
#define PART_OFF  7905280u    // 32 groups * 2048 * 256 bf16 = 33,554,432 B
// total = 41,459,712 B

// output offsets (f32 elements)
#define OUT_C    0      // [2,1024,3]
#define OUT_D    6144   // [2,1024,1]
#define OUT_EI   8192   // [128,2,32]
#define OUT_ND   16384  // [128,2,3]
#define OUT_MEAN 17152  // [128,2,8]
#define OUT_STD  19200  // [128,2,8]

__device__ __forceinline__ short f2bs(float x) {
  __hip_bfloat16 h = __float2bfloat16(x);
  union { __hip_bfloat16 hh; short s; } u; u.hh = h; return u.s;
}

// ============ kernel 0: fused prep = pack_weights + encdec + bwsum ============
// blocks 0..1919: pack; 1920..1951: encdec (4 nodes each); 1952..1959: bwsum
__global__ void prep(const float* __restrict__ f1w, const float* __restrict__ f2w,
                     const float* __restrict__ f3w, const float* __restrict__ f4w,
                     __hip_bfloat16* __restrict__ w1p, __hip_bfloat16* __restrict__ w2p,
                     __hip_bfloat16* __restrict__ w3p, __hip_bfloat16* __restrict__ w4p,
                     const float* __restrict__ t_ped, const float* __restrict__ pose,
                     const float* __restrict__ ec1w, const float* __restrict__ ec1b,
                     const float* __restrict__ ec21w, const float* __restrict__ ec21b,
                     const float* __restrict__ ec22w, const float* __restrict__ ec22b,
                     const float* __restrict__ dc1w, const float* __restrict__ dc1b,
                     const float* __restrict__ dc21w, const float* __restrict__ dc21b,
                     const float* __restrict__ dc22w, const float* __restrict__ dc22b,
                     const float* __restrict__ bwt,
                     float* __restrict__ out, float* __restrict__ ei_ws,
                     float* __restrict__ recip) {
  const int bid = blockIdx.x;
  const int tid = threadIdx.x;
  if (bid < 1920) {
    // ---------------- pack ----------------
    int id = bid * 256 + tid;
    union { __hip_bfloat16 h[8]; int4 v; } u;
    if (id < 98304) {                       // W1: [n][12 kc][64 o], K=95 padded to 96
      int n = id / 768, r = id % 768, kc = r >> 6, o = r & 63;
      #pragma unroll
      for (int e = 0; e < 8; e++) {
        int k = kc * 8 + e;
        float val = (k < 95) ? f1w[((size_t)n * 95 + k) * 64 + o] : 0.f;
        u.h[e] = __float2bfloat16(val);
      }
      reinterpret_cast<int4*>(w1p)[id] = u.v;
    } else if (id < 163840) {               // W2: [n][8][64]
      int id2 = id - 98304;
      int n = id2 / 512, r = id2 % 512, kc = r >> 6, o = r & 63;
      #pragma unroll
      for (int e = 0; e < 8; e++)
        u.h[e] = __float2bfloat16(f2w[((size_t)n * 64 + kc * 8 + e) * 64 + o]);
      reinterpret_cast<int4*>(w2p)[id2] = u.v;
    } else if (id < 229376) {               // W3
      int id3 = id - 163840;
      int n = id3 / 512, r = id3 % 512, kc = r >> 6, o = r & 63;
      #pragma unroll
      for (int e = 0; e < 8; e++)
        u.h[e] = __float2bfloat16(f3w[((size_t)n * 64 + kc * 8 + e) * 64 + o]);
      reinterpret_cast<int4*>(w3p)[id3] = u.v;
    } else {                                // W4: [n][8][256]
      int id4 = id - 229376;
      int n = id4 / 2048, r = id4 % 2048, kc = r >> 8, o = r & 255;
      #pragma unroll
      for (int e = 0; e < 8; e++)
        u.h[e] = __float2bfloat16(f4w[((size_t)n * 64 + kc * 8 + e) * 256 + o]);
      reinterpret_cast<int4*>(w4p)[id4] = u.v;
    }
  } else if (bid < 1952) {
    // ---------------- encdec: 4 nodes per block ----------------
    __shared__ float enc_in[4][2][88];
    __shared__ float net[4][2][64];
    __shared__ float dec_in[4][2][80];
    __shared__ float dnet[4][2][64];
    const int sub = tid >> 6, t = tid & 63;
    const int n = (bid - 1920) * 4 + sub;
    if (t < 32) { int b = t >> 4, i = t & 15; enc_in[sub][b][i] = t_ped[b * 16 + i]; }
    for (int idx = t; idx < 144; idx += 64) {
      int b = idx / 72, i = idx - b * 72;
      float pv = pose[idx];
      enc_in[sub][b][16 + i] = pv;
      dec_in[sub][b][8 + i] = pv;
    }
    __syncthreads();
    { // net = relu(enc_in @ ec1_w + b)
      float a0 = ec1b[n * 64 + t], a1 = a0;
      const float* w = ec1w + (size_t)n * 88 * 64 + t;
      for (int i = 0; i < 88; i++) { float wv = w[i * 64]; a0 += enc_in[sub][0][i] * wv; a1 += enc_in[sub][1][i] * wv; }
      net[sub][0][t] = fmaxf(a0, 0.f); net[sub][1][t] = fmaxf(a1, 0.f);
    }
    __syncthreads();
    if (t < 32) { // mean (t<16) / std (t>=16)
      int isd = t >> 4, b = (t >> 3) & 1, o = t & 7;
      const float* w = (isd ? ec22w : ec21w) + (size_t)n * 64 * 8 + o;
      float acc = (isd ? ec22b : ec21b)[n * 8 + o];
      for (int i = 0; i < 64; i++) acc += net[sub][b][i] * w[i * 8];
      if (isd) out[OUT_STD + (n * 2 + b) * 8 + o] = 1.f / (1.f + expf(-acc));
      else { out[OUT_MEAN + (n * 2 + b) * 8 + o] = acc; dec_in[sub][b][o] = acc; }
    }
    __syncthreads();
    { // dnet = relu(dec_in @ dc1_w + b)
      float a0 = dc1b[n * 64 + t], a1 = a0;
      const float* w = dc1w + (size_t)n * 80 * 64 + t;
      for (int i = 0; i < 80; i++) { float wv = w[i * 64]; a0 += dec_in[sub][0][i] * wv; a1 += dec_in[sub][1][i] * wv; }
      dnet[sub][0][t] = fmaxf(a0, 0.f); dnet[sub][1][t] = fmaxf(a1, 0.f);
    }
    __syncthreads();
    { // ei (no activation)
      int b = t >> 5, o = t & 31;
      const float* w = dc21w + (size_t)n * 64 * 32 + o;
      float acc = dc21b[n * 32 + o];
      for (int i = 0; i < 64; i++) acc += dnet[sub][b][i] * w[i * 32];
      out[OUT_EI + (n * 2 + b) * 32 + o] = acc;
      ei_ws[(n * 2 + b) * 32 + o] = acc;
    }
    if (t < 6) { // nodes_delta
      int b = t / 3, o = t - b * 3;
      const float* w = dc22w + (size_t)n * 64 * 3 + o;
      float acc = dc22b[n * 3 + o];
      for (int i = 0; i < 64; i++) acc += dnet[sub][b][i] * w[i * 3];
      out[OUT_ND + (n * 2 + b) * 3 + o] = acc;
    }
  } else {
    // ---------------- bwsum ----------------
    int r = (bid - 1952) * 256 + tid;  // r = b*1024+v
    float s = 0.f;
    for (int n = 0; n < 128; n++) s += bwt[n * 2048 + r];
    recip[r] = 1.f / (s + 128.f * 1e-7f);
  }
}

// ============ kernel 2: feature field (MFMA bf16) — barrier-free, wave-independent ============
// v4: occupancy 2x. grid = 32 groups (4 nodes) x 32 tiles (64 rows) = 1024 blocks,
// 4 waves/block -> 4096 waves = 16 waves/CU (4/SIMD, VGPR<=128). Partials in bf16
// (channel-permuted packed stores) keep ws + write traffic flat vs 16-group f32.
__launch_bounds__(256, 4)
__global__ void feature_field(const float* __restrict__ coords, const int* __restrict__ mask,
                              const float* __restrict__ bwt,
                              const __hip_bfloat16* __restrict__ w1p, const __hip_bfloat16* __restrict__ w2p,
                              const __hip_bfloat16* __restrict__ w3p, const __hip_bfloat16* __restrict__ w4p,
                              const float* __restrict__ f1b, const float* __restrict__ f2b,
                              const float* __restrict__ f3b, const float* __restrict__ f4b,
                              const float* __restrict__ ei_ws, const float* __restrict__ recip,
                              __hip_bfloat16* __restrict__ part) {
  __shared__ __align__(16) __hip_bfloat16 hbuf[4][16][72];  // per-wave 2304B slices

  const int tid = threadIdx.x;
  const int wv = tid >> 6;
  const int lane = tid & 63;
  const int l16 = lane & 15;
  const int kg = lane >> 4;
  const int g = blockIdx.x >> 5;                 // node group 0..31 (4 nodes each)
  const int row0 = (blockIdx.x & 31) * 64 + wv * 16;  // global row 0..2047
  const int b = row0 >> 10;
  const int v0 = row0 & 1023;

  const f32x4 zero4 = {0.f, 0.f, 0.f, 0.f};
  f32x4 pb[16];
  #pragma unroll
  for (int i = 0; i < 16; i++) pb[i] = zero4;

  for (int ni = 0; ni < 4; ni++) {
    const int n = (g << 2) + ni;
    // ---- A-fragments straight from global ----
    short8 a0, a1, a2;
    {
      const float* ep = ei_ws + ((n << 1) + b) * 32 + kg * 8;   // row-invariant
      #pragma unroll
      for (int e = 0; e < 8; e++) a0[e] = f2bs(ep[e]);
      const float* cp = coords + ((size_t)((n << 1) + b) * 1024 + v0 + l16) * 63;
      #pragma unroll
      for (int e = 0; e < 8; e++) a1[e] = f2bs(cp[kg * 8 + e]);
      #pragma unroll
      for (int e = 0; e < 8; e++) {
        int c = 32 + kg * 8 + e;
        a2[e] = (c < 63) ? f2bs(cp[c]) : (short)0;
      }
    }
    const __hip_bfloat16* w1n = w1p + (size_t)n * 6144;
    const __hip_bfloat16* w2n = w2p + (size_t)n * 4096;
    const __hip_bfloat16* w3n = w3p + (size_t)n * 4096;
    const __hip_bfloat16* w4n = w4p + (size_t)n * 16384;

    // ---- L1: [16x96] @ [96x64] ----
    {
      short8 bf[12];
      #pragma unroll
      for (int nt = 0; nt < 4; nt++)
        #pragma unroll
        for (int kt = 0; kt < 3; kt++)
          bf[nt * 3 + kt] = *reinterpret_cast<const short8*>(&w1n[((kt * 4 + kg) * 64 + nt * 16 + l16) * 8]);
      #pragma unroll
      for (int nt = 0; nt < 4; nt++) {
        f32x4 acc = zero4;
        acc = __builtin_amdgcn_mfma_f32_16x16x32_bf16(a0, bf[nt * 3 + 0], acc, 0, 0, 0);
        acc = __builtin_amdgcn_mfma_f32_16x16x32_bf16(a1, bf[nt * 3 + 1], acc, 0, 0, 0);
        acc = __builtin_amdgcn_mfma_f32_16x16x32_bf16(a2, bf[nt * 3 + 2], acc, 0, 0, 0);
        int col = nt * 16 + l16;
        float bias = f1b[(n << 6) + col];
        #pragma unroll
        for (int r = 0; r < 4; r++)
          hbuf[wv][kg * 4 + r][col] = __float2bfloat16(fmaxf(acc[r] + bias, 0.f));
      }
    }
    asm volatile("s_waitcnt lgkmcnt(0)");
    __builtin_amdgcn_wave_barrier();
    // ---- L2 ----
    {
      short8 ha[2];
      #pragma unroll
      for (int kt = 0; kt < 2; kt++)
        ha[kt] = *reinterpret_cast<const short8*>(&hbuf[wv][l16][kt * 32 + kg * 8]);
      __builtin_amdgcn_wave_barrier();
      short8 bf[8];
      #pragma unroll
      for (int nt = 0; nt < 4; nt++)
        #pragma unroll
        for (int kt = 0; kt < 2; kt++)
          bf[nt * 2 + kt] = *reinterpret_cast<const short8*>(&w2n[((kt * 4 + kg) * 64 + nt * 16 + l16) * 8]);
      #pragma unroll
      for (int nt = 0; nt < 4; nt++) {
        f32x4 acc = zero4;
        acc = __builtin_amdgcn_mfma_f32_16x16x32_bf16(ha[0], bf[nt * 2 + 0], acc, 0, 0, 0);
        acc = __builtin_amdgcn_mfma_f32_16x16x32_bf16(ha[1], bf[nt * 2 + 1], acc, 0, 0, 0);
        int col = nt * 16 + l16;
        float bias = f2b[(n << 6) + col];
        #pragma unroll
        for (int r = 0; r < 4; r++)
          hbuf[wv][kg * 4 + r][col] = __float2bfloat16(fmaxf(acc[r] + bias, 0.f));
      }
    }
    asm volatile("s_waitcnt lgkmcnt(0)");
    __builtin_amdgcn_wave_barrier();
    // ---- L3 ----
    {
      short8 ha[2];
      #pragma unroll
      for (int kt = 0; kt < 2; kt++)
        ha[kt] = *reinterpret_cast<const short8*>(&hbuf[wv][l16][kt * 32 + kg * 8]);
      __builtin_amdgcn_wave_barrier();
      short8 bf[8];
      #pragma unroll
      for (int nt = 0; nt < 4; nt++)
        #pragma unroll
        for (int kt = 0; kt < 2; kt++)
          bf[nt * 2 + kt] = *reinterpret_cast<const short8*>(&w3n[((kt * 4 + kg) * 64 + nt * 16 + l16) * 8]);
      #pragma unroll
      for (int nt = 0; nt < 4; nt++) {
        f32x4 acc = zero4;
        acc = __builtin_amdgcn_mfma_f32_16x16x32_bf16(ha[0], bf[nt * 2 + 0], acc, 0, 0, 0);
        acc = __builtin_amdgcn_mfma_f32_16x16x32_bf16(ha[1], bf[nt * 2 + 1], acc, 0, 0, 0);
        int col = nt * 16 + l16;
        float bias = f3b[(n << 6) + col];
        #pragma unroll
        for (int r = 0; r < 4; r++)
          hbuf[wv][kg * 4 + r][col] = __float2bfloat16(fmaxf(acc[r] + bias, 0.f));
      }
    }
    asm volatile("s_waitcnt lgkmcnt(0)");
    __builtin_amdgcn_wave_barrier();
    // ---- L4: [16x64] @ [64x256], fused mask*blend-weight ----
    {
      short8 ha[2];
      #pragma unroll
      for (int kt = 0; kt < 2; kt++)
        ha[kt] = *reinterpret_cast<const short8*>(&hbuf[wv][l16][kt * 32 + kg * 8]);
      __builtin_amdgcn_wave_barrier();
      float wrow[4];
      #pragma unroll
      for (int r = 0; r < 4; r++) {
        int gi = row0 + kg * 4 + r;
        float bwv = (bwt[(n << 11) + gi] + 1e-7f) * recip[gi];
        wrow[r] = (mask[(n << 11) + gi] != 0) ? bwv : 0.f;
      }
      #pragma unroll
      for (int c = 0; c < 4; c++) {
        short8 bf[8];
        #pragma unroll
        for (int nti = 0; nti < 4; nti++)
          #pragma unroll
          for (int kt = 0; kt < 2; kt++)
            bf[nti * 2 + kt] = *reinterpret_cast<const short8*>(&w4n[((kt * 4 + kg) * 256 + (c * 4 + nti) * 16 + l16) * 8]);
        #pragma unroll
        for (int nti = 0; nti < 4; nti++) {
          f32x4 acc = zero4;
          acc = __builtin_amdgcn_mfma_f32_16x16x32_bf16(ha[0], bf[nti * 2 + 0], acc, 0, 0, 0);
          acc = __builtin_amdgcn_mfma_f32_16x16x32_bf16(ha[1], bf[nti * 2 + 1], acc, 0, 0, 0);
          int nt = c * 4 + nti;
          float bias = f4b[(n << 8) + nt * 16 + l16];
          #pragma unroll
          for (int r = 0; r < 4; r++) {
            float fv = fmaxf(acc[r] + bias, 0.f);
            pb[nt][r] += wrow[r] * fv;
          }
        }
      }
    }
    __builtin_amdgcn_wave_barrier();  // keep next-node L1 writes after this node's L4 reads
  }
  // ---- write per-group partial blend (bf16, channel-permuted: idx = l16*16 + nt) ----
  {
    __hip_bfloat16* pr = part + ((size_t)(g * 2048 + row0 + kg * 4)) * 256 + l16 * 16;
    #pragma unroll
    for (int r = 0; r < 4; r++) {
      union { __hip_bfloat16 h[16]; int4 v[2]; } u;
      #pragma unroll
      for (int nt = 0; nt < 16; nt++) u.h[nt] = __float2bfloat16(pb[nt][r]);
      int4* dst = reinterpret_cast<int4*>(pr + (size_t)r * 256);
      dst[0] = u.v[0];
      dst[1] = u.v[1];
    }
  }
}

// ============ kernel 3: reduce partials (32 groups, bf16, permuted) + NeRF head ============
__global__ void head(const __hip_bfloat16* __restrict__ part,
                     const float* __restrict__ c1w, const float* __restrict__ c1b,
                     const float* __restrict__ c2w, const float* __restrict__ c2b,
                     const float* __restrict__ d1w, const float* __restrict__ d1b,
                     float* __restrict__ out) {
  __shared__ float fbs[256];
  __shared__ float ncs[64];
  int row = blockIdx.x;  // 0..2047
  int t = threadIdx.x;
  // ff stored channel ch at permuted index (ch&15)*16 + (ch>>4)
  int idx = ((t & 15) << 4) + (t >> 4);
  float fb = 0.f;
  for (int gi = 0; gi < 32; gi++)
    fb += __bfloat162float(part[((size_t)gi * 2048 + row) * 256 + idx]);
  fbs[t] = fb;
  __syncthreads();
  if (t < 64) {
    float acc = c1b[t];
    for (int c = 0; c < 256; c++) acc += fbs[c] * c1w[c * 64 + t];
    ncs[t] = fmaxf(acc, 0.f);
  } else if (t >= 192) {  // one wave computes d
    int l = t - 192;
    float acc = 0.f;
    for (int c = l; c < 256; c += 64) acc += fbs[c] * d1w[c];
    for (int off = 32; off > 0; off >>= 1) acc += __shfl_down(acc, off);
    if (l == 0) out[OUT_D + row] = fmaxf(acc + d1b[0], 0.f);
  }
  __syncthreads();
  if (t < 3) {
    float acc = c2b[t];
    for (int i = 0; i < 64; i++) acc += ncs[i] * c2w[i * 3 + t];
    out[OUT_C + row * 3 + t] = acc;
  }
}

extern "C" void kernel_launch(void* const* d_in, const int* in_sizes, int n_in,
                              void* d_out, int out_size, void* d_ws, size_t ws_size,
                              hipStream_t stream) {
  (void)in_sizes; (void)n_in; (void)out_size; (void)ws_size;
  const float* t_ped  = (const float*)d_in[0];
  const float* pose   = (const float*)d_in[1];
  const float* coords = (const float*)d_in[2];
  const int*   maskp  = (const int*)d_in[3];
  const float* bwt    = (const float*)d_in[4];
  const float* ec1w = (const float*)d_in[5],  *ec1b = (const float*)d_in[6];
  const float* ec21w = (const float*)d_in[7], *ec21b = (const float*)d_in[8];
  const float* ec22w = (const float*)d_in[9], *ec22b = (const float*)d_in[10];
  const float* dc1w = (const float*)d_in[11], *dc1b = (const float*)d_in[12];
  const float* dc21w = (const float*)d_in[13], *dc21b = (const float*)d_in[14];
  const float* dc22w = (const float*)d_in[15], *dc22b = (const float*)d_in[16];
  const float* f1w = (const float*)d_in[17], *f1b = (const float*)d_in[18];
  const float* f2w = (const float*)d_in[19], *f2b = (const float*)d_in[20];
  const float* f3w = (const float*)d_in[21], *f3b = (const float*)d_in[22];
  const float* f4w = (const float*)d_in[23], *f4b = (const float*)d_in[24];
  const float* c1w = (const float*)d_in[25], *c1b = (const float*)d_in[26];
  const float* c2w = (const float*)d_in[27], *c2b = (const float*)d_in[28];
  const float* d1w = (const float*)d_in[29], *d1b = (const float*)d_in[30];
  float* out = (float*)d_out;
  char* ws = (char*)d_ws;
  __hip_bfloat16* w1p = (__hip_bfloat16*)(ws + W1P_OFF);
  __hip_bfloat16* w2p = (__hip_bfloat16*)(ws + W2P_OFF);
  __hip_bfloat16* w3p = (__hip_bfloat16*)(ws + W3P_OFF);
  __hip_bfloat16* w4p = (__hip_bfloat16*)(ws + W4P_OFF);
  float* ei_ws = (float*)(ws + EI_OFF);
  float* recip_ws = (float*)(ws + RECIP_OFF);
  __hip_bfloat16* part16 = (__hip_bfloat16*)(ws + PART_OFF);

  hipLaunchKernelGGL(prep, dim3(1960), dim3(256), 0, stream,
                     f1w, f2w, f3w, f4w, w1p, w2p, w3p, w4p,
                     t_ped, pose, ec1w, ec1b, ec21w, ec21b, ec22w, ec22b,
                     dc1w, dc1b, dc21w, dc21b, dc22w, dc22b,
                     bwt, out, ei_ws, recip_ws);
  hipLaunchKernelGGL(feature_field, dim3(1024), dim3(256), 0, stream,
                     coords, maskp, bwt, w1p, w2p, w3p, w4p,
                     f1b, f2b, f3b, f4b, ei_ws, recip_ws, part16);
  hipLaunchKernelGGL(head, dim3(2048), dim3(256), 0, stream,
                     part16, c1w, c1b, c2w, c2b, d1w, d1b, out);
}

// Round 8
// 261.170 us; speedup vs baseline: 1.4293x; 1.4293x over previous
//
#include <hip/hip_runtime.h>
#include <hip/hip_bf16.h>
#include <math.h>

typedef __attribute__((ext_vector_type(8))) short short8;
typedef __attribute__((ext_vector_type(4))) float f32x4;

// ---------------- workspace layout (bytes) ----------------
#define W1P_OFF   0u          // 128*12*64*8 bf16 = 1,572,864 B
#define W2P_OFF   1572864u    // 128*8*64*8  bf16 = 1,048,576 B
#define W3P_OFF   2621440u
#define W4P_OFF   3670016u    // 128*8*256*8 bf16 = 4,194,304 B
#define EI_OFF    7864320u    // 128*2*32 f32 = 32,768 B
#define RECIP_OFF 7897088u    // 2048 f32
#define PART_OFF  7905280u    // 32 groups * 2048 * 256 bf16 = 33,554,432 B
// total = 41,459,712 B

// output offsets (f32 elements)
#define OUT_C    0      // [2,1024,3]
#define OUT_D    6144   // [2,1024,1]
#define OUT_EI   8192   // [128,2,32]
#define OUT_ND   16384  // [128,2,3]
#define OUT_MEAN 17152  // [128,2,8]
#define OUT_STD  19200  // [128,2,8]

__device__ __forceinline__ short f2bs(float x) {
  __hip_bfloat16 h = __float2bfloat16(x);
  union { __hip_bfloat16 hh; short s; } u; u.hh = h; return u.s;
}

// ============ kernel 0: fused prep = pack_weights + encdec + bwsum ============
// blocks 0..1919: pack; 1920..1951: encdec (4 nodes each); 1952..1959: bwsum
__global__ void prep(const float* __restrict__ f1w, const float* __restrict__ f2w,
                     const float* __restrict__ f3w, const float* __restrict__ f4w,
                     __hip_bfloat16* __restrict__ w1p, __hip_bfloat16* __restrict__ w2p,
                     __hip_bfloat16* __restrict__ w3p, __hip_bfloat16* __restrict__ w4p,
                     const float* __restrict__ t_ped, const float* __restrict__ pose,
                     const float* __restrict__ ec1w, const float* __restrict__ ec1b,
                     const float* __restrict__ ec21w, const float* __restrict__ ec21b,
                     const float* __restrict__ ec22w, const float* __restrict__ ec22b,
                     const float* __restrict__ dc1w, const float* __restrict__ dc1b,
                     const float* __restrict__ dc21w, const float* __restrict__ dc21b,
                     const float* __restrict__ dc22w, const float* __restrict__ dc22b,
                     const float* __restrict__ bwt,
                     float* __restrict__ out, float* __restrict__ ei_ws,
                     float* __restrict__ recip) {
  const int bid = blockIdx.x;
  const int tid = threadIdx.x;
  if (bid < 1920) {
    // ---------------- pack ----------------
    int id = bid * 256 + tid;
    union { __hip_bfloat16 h[8]; int4 v; } u;
    if (id < 98304) {                       // W1: [n][12 kc][64 o], K=95 padded to 96
      int n = id / 768, r = id % 768, kc = r >> 6, o = r & 63;
      #pragma unroll
      for (int e = 0; e < 8; e++) {
        int k = kc * 8 + e;
        float val = (k < 95) ? f1w[((size_t)n * 95 + k) * 64 + o] : 0.f;
        u.h[e] = __float2bfloat16(val);
      }
      reinterpret_cast<int4*>(w1p)[id] = u.v;
    } else if (id < 163840) {               // W2: [n][8][64]
      int id2 = id - 98304;
      int n = id2 / 512, r = id2 % 512, kc = r >> 6, o = r & 63;
      #pragma unroll
      for (int e = 0; e < 8; e++)
        u.h[e] = __float2bfloat16(f2w[((size_t)n * 64 + kc * 8 + e) * 64 + o]);
      reinterpret_cast<int4*>(w2p)[id2] = u.v;
    } else if (id < 229376) {               // W3
      int id3 = id - 163840;
      int n = id3 / 512, r = id3 % 512, kc = r >> 6, o = r & 63;
      #pragma unroll
      for (int e = 0; e < 8; e++)
        u.h[e] = __float2bfloat16(f3w[((size_t)n * 64 + kc * 8 + e) * 64 + o]);
      reinterpret_cast<int4*>(w3p)[id3] = u.v;
    } else {                                // W4: [n][8][256]
      int id4 = id - 229376;
      int n = id4 / 2048, r = id4 % 2048, kc = r >> 8, o = r & 255;
      #pragma unroll
      for (int e = 0; e < 8; e++)
        u.h[e] = __float2bfloat16(f4w[((size_t)n * 64 + kc * 8 + e) * 256 + o]);
      reinterpret_cast<int4*>(w4p)[id4] = u.v;
    }
  } else if (bid < 1952) {
    // ---------------- encdec: 4 nodes per block ----------------
    __shared__ float enc_in[4][2][88];
    __shared__ float net[4][2][64];
    __shared__ float dec_in[4][2][80];
    __shared__ float dnet[4][2][64];
    const int sub = tid >> 6, t = tid & 63;
    const int n = (bid - 1920) * 4 + sub;
    if (t < 32) { int b = t >> 4, i = t & 15; enc_in[sub][b][i] = t_ped[b * 16 + i]; }
    for (int idx = t; idx < 144; idx += 64) {
      int b = idx / 72, i = idx - b * 72;
      float pv = pose[idx];
      enc_in[sub][b][16 + i] = pv;
      dec_in[sub][b][8 + i] = pv;
    }
    __syncthreads();
    { // net = relu(enc_in @ ec1_w + b)
      float a0 = ec1b[n * 64 + t], a1 = a0;
      const float* w = ec1w + (size_t)n * 88 * 64 + t;
      for (int i = 0; i < 88; i++) { float wv = w[i * 64]; a0 += enc_in[sub][0][i] * wv; a1 += enc_in[sub][1][i] * wv; }
      net[sub][0][t] = fmaxf(a0, 0.f); net[sub][1][t] = fmaxf(a1, 0.f);
    }
    __syncthreads();
    if (t < 32) { // mean (t<16) / std (t>=16)
      int isd = t >> 4, b = (t >> 3) & 1, o = t & 7;
      const float* w = (isd ? ec22w : ec21w) + (size_t)n * 64 * 8 + o;
      float acc = (isd ? ec22b : ec21b)[n * 8 + o];
      for (int i = 0; i < 64; i++) acc += net[sub][b][i] * w[i * 8];
      if (isd) out[OUT_STD + (n * 2 + b) * 8 + o] = 1.f / (1.f + expf(-acc));
      else { out[OUT_MEAN + (n * 2 + b) * 8 + o] = acc; dec_in[sub][b][o] = acc; }
    }
    __syncthreads();
    { // dnet = relu(dec_in @ dc1_w + b)
      float a0 = dc1b[n * 64 + t], a1 = a0;
      const float* w = dc1w + (size_t)n * 80 * 64 + t;
      for (int i = 0; i < 80; i++) { float wv = w[i * 64]; a0 += dec_in[sub][0][i] * wv; a1 += dec_in[sub][1][i] * wv; }
      dnet[sub][0][t] = fmaxf(a0, 0.f); dnet[sub][1][t] = fmaxf(a1, 0.f);
    }
    __syncthreads();
    { // ei (no activation)
      int b = t >> 5, o = t & 31;
      const float* w = dc21w + (size_t)n * 64 * 32 + o;
      float acc = dc21b[n * 32 + o];
      for (int i = 0; i < 64; i++) acc += dnet[sub][b][i] * w[i * 32];
      out[OUT_EI + (n * 2 + b) * 32 + o] = acc;
      ei_ws[(n * 2 + b) * 32 + o] = acc;
    }
    if (t < 6) { // nodes_delta
      int b = t / 3, o = t - b * 3;
      const float* w = dc22w + (size_t)n * 64 * 3 + o;
      float acc = dc22b[n * 3 + o];
      for (int i = 0; i < 64; i++) acc += dnet[sub][b][i] * w[i * 3];
      out[OUT_ND + (n * 2 + b) * 3 + o] = acc;
    }
  } else {
    // ---------------- bwsum ----------------
    int r = (bid - 1952) * 256 + tid;  // r = b*1024+v
    float s = 0.f;
    for (int n = 0; n < 128; n++) s += bwt[n * 2048 + r];
    recip[r] = 1.f / (s + 128.f * 1e-7f);
  }
}

// ============ kernel 2: feature field (MFMA bf16) — barrier-free, wave-independent ============
// v5: v4 structure (32 groups x 4 nodes/wave, 1024 blocks) but WITHOUT the forced
// (256,4) launch bound that spilled pb[] to scratch (round 7: VGPR 120->64,
// WRITE 33->258 MB, 2.6x slowdown). (256,2) lets the allocator keep ~120 VGPR;
// HW can still reach 4 waves/SIMD (4x120 <= 512) and 4 blocks/CU (LDS 9.2 KB).
__launch_bounds__(256, 2)
__global__ void feature_field(const float* __restrict__ coords, const int* __restrict__ mask,
                              const float* __restrict__ bwt,
                              const __hip_bfloat16* __restrict__ w1p, const __hip_bfloat16* __restrict__ w2p,
                              const __hip_bfloat16* __restrict__ w3p, const __hip_bfloat16* __restrict__ w4p,
                              const float* __restrict__ f1b, const float* __restrict__ f2b,
                              const float* __restrict__ f3b, const float* __restrict__ f4b,
                              const float* __restrict__ ei_ws, const float* __restrict__ recip,
                              __hip_bfloat16* __restrict__ part) {
  __shared__ __align__(16) __hip_bfloat16 hbuf[4][16][72];  // per-wave 2304B slices

  const int tid = threadIdx.x;
  const int wv = tid >> 6;
  const int lane = tid & 63;
  const int l16 = lane & 15;
  const int kg = lane >> 4;
  const int g = blockIdx.x >> 5;                 // node group 0..31 (4 nodes each)
  const int row0 = (blockIdx.x & 31) * 64 + wv * 16;  // global row 0..2047
  const int b = row0 >> 10;
  const int v0 = row0 & 1023;

  const f32x4 zero4 = {0.f, 0.f, 0.f, 0.f};
  f32x4 pb[16];
  #pragma unroll
  for (int i = 0; i < 16; i++) pb[i] = zero4;

  for (int ni = 0; ni < 4; ni++) {
    const int n = (g << 2) + ni;
    // ---- A-fragments straight from global ----
    short8 a0, a1, a2;
    {
      const float* ep = ei_ws + ((n << 1) + b) * 32 + kg * 8;   // row-invariant
      #pragma unroll
      for (int e = 0; e < 8; e++) a0[e] = f2bs(ep[e]);
      const float* cp = coords + ((size_t)((n << 1) + b) * 1024 + v0 + l16) * 63;
      #pragma unroll
      for (int e = 0; e < 8; e++) a1[e] = f2bs(cp[kg * 8 + e]);
      #pragma unroll
      for (int e = 0; e < 8; e++) {
        int c = 32 + kg * 8 + e;
        a2[e] = (c < 63) ? f2bs(cp[c]) : (short)0;
      }
    }
    const __hip_bfloat16* w1n = w1p + (size_t)n * 6144;
    const __hip_bfloat16* w2n = w2p + (size_t)n * 4096;
    const __hip_bfloat16* w3n = w3p + (size_t)n * 4096;
    const __hip_bfloat16* w4n = w4p + (size_t)n * 16384;

    // ---- L1: [16x96] @ [96x64] ----
    {
      short8 bf[12];
      #pragma unroll
      for (int nt = 0; nt < 4; nt++)
        #pragma unroll
        for (int kt = 0; kt < 3; kt++)
          bf[nt * 3 + kt] = *reinterpret_cast<const short8*>(&w1n[((kt * 4 + kg) * 64 + nt * 16 + l16) * 8]);
      #pragma unroll
      for (int nt = 0; nt < 4; nt++) {
        f32x4 acc = zero4;
        acc = __builtin_amdgcn_mfma_f32_16x16x32_bf16(a0, bf[nt * 3 + 0], acc, 0, 0, 0);
        acc = __builtin_amdgcn_mfma_f32_16x16x32_bf16(a1, bf[nt * 3 + 1], acc, 0, 0, 0);
        acc = __builtin_amdgcn_mfma_f32_16x16x32_bf16(a2, bf[nt * 3 + 2], acc, 0, 0, 0);
        int col = nt * 16 + l16;
        float bias = f1b[(n << 6) + col];
        #pragma unroll
        for (int r = 0; r < 4; r++)
          hbuf[wv][kg * 4 + r][col] = __float2bfloat16(fmaxf(acc[r] + bias, 0.f));
      }
    }
    asm volatile("s_waitcnt lgkmcnt(0)");
    __builtin_amdgcn_wave_barrier();
    // ---- L2 ----
    {
      short8 ha[2];
      #pragma unroll
      for (int kt = 0; kt < 2; kt++)
        ha[kt] = *reinterpret_cast<const short8*>(&hbuf[wv][l16][kt * 32 + kg * 8]);
      __builtin_amdgcn_wave_barrier();
      short8 bf[8];
      #pragma unroll
      for (int nt = 0; nt < 4; nt++)
        #pragma unroll
        for (int kt = 0; kt < 2; kt++)
          bf[nt * 2 + kt] = *reinterpret_cast<const short8*>(&w2n[((kt * 4 + kg) * 64 + nt * 16 + l16) * 8]);
      #pragma unroll
      for (int nt = 0; nt < 4; nt++) {
        f32x4 acc = zero4;
        acc = __builtin_amdgcn_mfma_f32_16x16x32_bf16(ha[0], bf[nt * 2 + 0], acc, 0, 0, 0);
        acc = __builtin_amdgcn_mfma_f32_16x16x32_bf16(ha[1], bf[nt * 2 + 1], acc, 0, 0, 0);
        int col = nt * 16 + l16;
        float bias = f2b[(n << 6) + col];
        #pragma unroll
        for (int r = 0; r < 4; r++)
          hbuf[wv][kg * 4 + r][col] = __float2bfloat16(fmaxf(acc[r] + bias, 0.f));
      }
    }
    asm volatile("s_waitcnt lgkmcnt(0)");
    __builtin_amdgcn_wave_barrier();
    // ---- L3 ----
    {
      short8 ha[2];
      #pragma unroll
      for (int kt = 0; kt < 2; kt++)
        ha[kt] = *reinterpret_cast<const short8*>(&hbuf[wv][l16][kt * 32 + kg * 8]);
      __builtin_amdgcn_wave_barrier();
      short8 bf[8];
      #pragma unroll
      for (int nt = 0; nt < 4; nt++)
        #pragma unroll
        for (int kt = 0; kt < 2; kt++)
          bf[nt * 2 + kt] = *reinterpret_cast<const short8*>(&w3n[((kt * 4 + kg) * 64 + nt * 16 + l16) * 8]);
      #pragma unroll
      for (int nt = 0; nt < 4; nt++) {
        f32x4 acc = zero4;
        acc = __builtin_amdgcn_mfma_f32_16x16x32_bf16(ha[0], bf[nt * 2 + 0], acc, 0, 0, 0);
        acc = __builtin_amdgcn_mfma_f32_16x16x32_bf16(ha[1], bf[nt * 2 + 1], acc, 0, 0, 0);
        int col = nt * 16 + l16;
        float bias = f3b[(n << 6) + col];
        #pragma unroll
        for (int r = 0; r < 4; r++)
          hbuf[wv][kg * 4 + r][col] = __float2bfloat16(fmaxf(acc[r] + bias, 0.f));
      }
    }
    asm volatile("s_waitcnt lgkmcnt(0)");
    __builtin_amdgcn_wave_barrier();
    // ---- L4: [16x64] @ [64x256], fused mask*blend-weight ----
    {
      short8 ha[2];
      #pragma unroll
      for (int kt = 0; kt < 2; kt++)
        ha[kt] = *reinterpret_cast<const short8*>(&hbuf[wv][l16][kt * 32 + kg * 8]);
      __builtin_amdgcn_wave_barrier();
      float wrow[4];
      #pragma unroll
      for (int r = 0; r < 4; r++) {
        int gi = row0 + kg * 4 + r;
        float bwv = (bwt[(n << 11) + gi] + 1e-7f) * recip[gi];
        wrow[r] = (mask[(n << 11) + gi] != 0) ? bwv : 0.f;
      }
      #pragma unroll
      for (int c = 0; c < 4; c++) {
        short8 bf[8];
        #pragma unroll
        for (int nti = 0; nti < 4; nti++)
          #pragma unroll
          for (int kt = 0; kt < 2; kt++)
            bf[nti * 2 + kt] = *reinterpret_cast<const short8*>(&w4n[((kt * 4 + kg) * 256 + (c * 4 + nti) * 16 + l16) * 8]);
        #pragma unroll
        for (int nti = 0; nti < 4; nti++) {
          f32x4 acc = zero4;
          acc = __builtin_amdgcn_mfma_f32_16x16x32_bf16(ha[0], bf[nti * 2 + 0], acc, 0, 0, 0);
          acc = __builtin_amdgcn_mfma_f32_16x16x32_bf16(ha[1], bf[nti * 2 + 1], acc, 0, 0, 0);
          int nt = c * 4 + nti;
          float bias = f4b[(n << 8) + nt * 16 + l16];
          #pragma unroll
          for (int r = 0; r < 4; r++) {
            float fv = fmaxf(acc[r] + bias, 0.f);
            pb[nt][r] += wrow[r] * fv;
          }
        }
      }
    }
    __builtin_amdgcn_wave_barrier();  // keep next-node L1 writes after this node's L4 reads
  }
  // ---- write per-group partial blend (bf16, channel-permuted: idx = l16*16 + nt) ----
  {
    __hip_bfloat16* pr = part + ((size_t)(g * 2048 + row0 + kg * 4)) * 256 + l16 * 16;
    #pragma unroll
    for (int r = 0; r < 4; r++) {
      union { __hip_bfloat16 h[16]; int4 v[2]; } u;
      #pragma unroll
      for (int nt = 0; nt < 16; nt++) u.h[nt] = __float2bfloat16(pb[nt][r]);
      int4* dst = reinterpret_cast<int4*>(pr + (size_t)r * 256);
      dst[0] = u.v[0];
      dst[1] = u.v[1];
    }
  }
}

// ============ kernel 3: reduce partials (32 groups, bf16, permuted) + NeRF head ============
__global__ void head(const __hip_bfloat16* __restrict__ part,
                     const float* __restrict__ c1w, const float* __restrict__ c1b,
                     const float* __restrict__ c2w, const float* __restrict__ c2b,
                     const float* __restrict__ d1w, const float* __restrict__ d1b,
                     float* __restrict__ out) {
  __shared__ float fbs[256];
  __shared__ float ncs[64];
  int row = blockIdx.x;  // 0..2047
  int t = threadIdx.x;
  // ff stored channel ch at permuted index (ch&15)*16 + (ch>>4)
  int idx = ((t & 15) << 4) + (t >> 4);
  float fb = 0.f;
  for (int gi = 0; gi < 32; gi++)
    fb += __bfloat162float(part[((size_t)gi * 2048 + row) * 256 + idx]);
  fbs[t] = fb;
  __syncthreads();
  if (t < 64) {
    float acc = c1b[t];
    for (int c = 0; c < 256; c++) acc += fbs[c] * c1w[c * 64 + t];
    ncs[t] = fmaxf(acc, 0.f);
  } else if (t >= 192) {  // one wave computes d
    int l = t - 192;
    float acc = 0.f;
    for (int c = l; c < 256; c += 64) acc += fbs[c] * d1w[c];
    for (int off = 32; off > 0; off >>= 1) acc += __shfl_down(acc, off);
    if (l == 0) out[OUT_D + row] = fmaxf(acc + d1b[0], 0.f);
  }
  __syncthreads();
  if (t < 3) {
    float acc = c2b[t];
    for (int i = 0; i < 64; i++) acc += ncs[i] * c2w[i * 3 + t];
    out[OUT_C + row * 3 + t] = acc;
  }
}

extern "C" void kernel_launch(void* const* d_in, const int* in_sizes, int n_in,
                              void* d_out, int out_size, void* d_ws, size_t ws_size,
                              hipStream_t stream) {
  (void)in_sizes; (void)n_in; (void)out_size; (void)ws_size;
  const float* t_ped  = (const float*)d_in[0];
  const float* pose   = (const float*)d_in[1];
  const float* coords = (const float*)d_in[2];
  const int*   maskp  = (const int*)d_in[3];
  const float* bwt    = (const float*)d_in[4];
  const float* ec1w = (const float*)d_in[5],  *ec1b = (const float*)d_in[6];
  const float* ec21w = (const float*)d_in[7], *ec21b = (const float*)d_in[8];
  const float* ec22w = (const float*)d_in[9], *ec22b = (const float*)d_in[10];
  const float* dc1w = (const float*)d_in[11], *dc1b = (const float*)d_in[12];
  const float* dc21w = (const float*)d_in[13], *dc21b = (const float*)d_in[14];
  const float* dc22w = (const float*)d_in[15], *dc22b = (const float*)d_in[16];
  const float* f1w = (const float*)d_in[17], *f1b = (const float*)d_in[18];
  const float* f2w = (const float*)d_in[19], *f2b = (const float*)d_in[20];
  const float* f3w = (const float*)d_in[21], *f3b = (const float*)d_in[22];
  const float* f4w = (const float*)d_in[23], *f4b = (const float*)d_in[24];
  const float* c1w = (const float*)d_in[25], *c1b = (const float*)d_in[26];
  const float* c2w = (const float*)d_in[27], *c2b = (const float*)d_in[28];
  const float* d1w = (const float*)d_in[29], *d1b = (const float*)d_in[30];
  float* out = (float*)d_out;
  char* ws = (char*)d_ws;
  __hip_bfloat16* w1p = (__hip_bfloat16*)(ws + W1P_OFF);
  __hip_bfloat16* w2p = (__hip_bfloat16*)(ws + W2P_OFF);
  __hip_bfloat16* w3p = (__hip_bfloat16*)(ws + W3P_OFF);
  __hip_bfloat16* w4p = (__hip_bfloat16*)(ws + W4P_OFF);
  float* ei_ws = (float*)(ws + EI_OFF);
  float* recip_ws = (float*)(ws + RECIP_OFF);
  __hip_bfloat16* part16 = (__hip_bfloat16*)(ws + PART_OFF);

  hipLaunchKernelGGL(prep, dim3(1960), dim3(256), 0, stream,
                     f1w, f2w, f3w, f4w, w1p, w2p, w3p, w4p,
                     t_ped, pose, ec1w, ec1b, ec21w, ec21b, ec22w, ec22b,
                     dc1w, dc1b, dc21w, dc21b, dc22w, dc22b,
                     bwt, out, ei_ws, recip_ws);
  hipLaunchKernelGGL(feature_field, dim3(1024), dim3(256), 0, stream,
                     coords, maskp, bwt, w1p, w2p, w3p, w4p,
                     f1b, f2b, f3b, f4b, ei_ws, recip_ws, part16);
  hipLaunchKernelGGL(head, dim3(2048), dim3(256), 0, stream,
                     part16, c1w, c1b, c2w, c2b, d1w, d1b, out);
}